// Round 2
// baseline (132.497 us; speedup 1.0000x reference)
//
#include <hip/hip_runtime.h>
#include <hip/hip_bf16.h>

#define B_ROWS 4096
#define TWOB   8192
#define DIM    256
#define INV_T  14.285714285714286f  // 1/0.07

#define BM 128
#define BN 128
#define NSTRIP 8
#define CT_PER_STRIP 8    // (8192/128)/NSTRIP

typedef __bf16 bf16x8 __attribute__((ext_vector_type(8)));
typedef float  f32x4  __attribute__((ext_vector_type(4)));

// ---------------- kernel 1: row L2-normalize, fp32 -> bf16 ----------------
// Also zeroes the finalize accumulators (ws is re-poisoned 0xAA before every launch).
__global__ __launch_bounds__(256) void normalize_k(const float* __restrict__ zi,
                                                   const float* __restrict__ zj,
                                                   unsigned short* __restrict__ zn,
                                                   float* __restrict__ loss_acc,
                                                   unsigned int* __restrict__ counter) {
    if (blockIdx.x == 0 && threadIdx.x == 0) {
        loss_acc[0] = 0.0f;
        counter[0]  = 0u;
    }
    int wave = threadIdx.x >> 6;
    int lane = threadIdx.x & 63;
    int row  = blockIdx.x * 4 + wave;             // 2048 blocks * 4 waves = 8192 rows
    const float* src = (row < B_ROWS) ? (zi + (size_t)row * DIM)
                                      : (zj + (size_t)(row - B_ROWS) * DIM);
    float4 v = reinterpret_cast<const float4*>(src)[lane];   // 64 lanes * 4 = 256
    float ss = v.x * v.x + v.y * v.y + v.z * v.z + v.w * v.w;
#pragma unroll
    for (int off = 32; off >= 1; off >>= 1) ss += __shfl_xor(ss, off);
    float norm = sqrtf(ss);
    norm = fmaxf(norm, 1e-8f);                    // COS_EPS
    float inv = 1.0f / norm;
    ushort4 o;
    o.x = __builtin_bit_cast(unsigned short, __float2bfloat16(v.x * inv));
    o.y = __builtin_bit_cast(unsigned short, __float2bfloat16(v.y * inv));
    o.z = __builtin_bit_cast(unsigned short, __float2bfloat16(v.z * inv));
    o.w = __builtin_bit_cast(unsigned short, __float2bfloat16(v.w * inv));
    reinterpret_cast<ushort4*>(zn)[(size_t)row * 64 + lane] = o;
}

// ---------------- kernel 2: flash NT-Xent main (barrier-free K loop) ----------------
// zn is 4 MB bf16 -> fully L2-resident. B fragments are therefore loaded DIRECTLY
// from global into VGPRs (16x16x32 B-operand layout: lane l <- zn[col+(l&15)]
// [kt*32+(l>>4)*8..+8] = one global_load_dwordx4 per lane). This deletes the B LDS
// double-buffer and with it ALL per-kt __syncthreads (64/block) whose
// vmcnt(0)+lgkmcnt(0) drains lockstepped the waves (R0: MfmaUtil 26%). A stays
// LDS-resident, staged ONCE per block with the proven involution swizzle.
// LDS = 64 KB -> 2 blocks/CU; VGPR cap 256 (launch_bounds(256,2)) gives the
// compiler headroom to hoist/pipeline B loads across the unrolled kt loop.
__global__ __launch_bounds__(256, 2) void ntxent_main(const unsigned short* __restrict__ znu,
                                                      float* __restrict__ pos,
                                                      float* __restrict__ strip_sums) {
    const __bf16* zn = (const __bf16*)znu;
    __shared__ __attribute__((aligned(16))) __bf16 As[8][BM * 32];   // 8 kt-chunks x 8 KB = 64 KB

    const int tid  = threadIdx.x;
    const int wave = tid >> 6;
    const int lane = tid & 63;
    const int wr = wave >> 1, wc = wave & 1;
    const int quad = lane >> 4, lc = lane & 15;
    const int rt    = blockIdx.x;        // row-tile 0..63
    const int strip = blockIdx.y;        // 0..NSTRIP-1
    const int row0  = rt * BM;
    const int posTile = (rt + 32) & 63;  // col-tile holding (row+4096) mod 8192

    // staging: per-lane global element offsets for this wave's two 1KB chunks per stage.
    // chunk c = j*64+lane -> (m=c>>2, kc_lds=c&3); source kc_g = kc_lds ^ sw(m)  (involution)
    int stg_off[2];
#pragma unroll
    for (int t = 0; t < 2; ++t) {
        int c  = (wave * 2 + t) * 64 + lane;
        int m  = c >> 2;
        int kc = (c & 3) ^ ((m & 3) ^ ((m >> 2) & 3));
        stg_off[t] = m * DIM + kc * 8;
    }

    // ---- prologue: stage full A (8 chunks), one barrier, then never again ----
#pragma unroll
    for (int kt = 0; kt < 8; ++kt) {
#pragma unroll
        for (int t = 0; t < 2; ++t) {
            const int j = wave * 2 + t;
            const __bf16* ga = zn + row0 * DIM + kt * 32 + stg_off[t];
            __builtin_amdgcn_global_load_lds(
                (const __attribute__((address_space(1))) void*)ga,
                (__attribute__((address_space(3))) void*)((char*)As + kt * 8192 + j * 1024), 16, 0, 0);
        }
    }

    // fragment-read byte offsets within one 8KB A chunk (swizzle depends only on m&15 == lc)
    const int sw    = (lc & 3) ^ ((lc >> 2) & 3);
    const int aBase = (wr * 64 + lc) * 64 + ((quad ^ sw) * 16);
    // B fragment base: lane l reads row (col0 + wc*64 + ni*16 + lc), bytes kt*64 + quad*16
    const char* bRow = (const char*)zn + (size_t)(wc * 64 + lc) * (DIM * 2) + quad * 16;

    float rsum[4][4];
#pragma unroll
    for (int mi = 0; mi < 4; ++mi)
#pragma unroll
        for (int r = 0; r < 4; ++r) rsum[mi][r] = 0.0f;

    __syncthreads();   // the ONLY staging barrier: A tile visible to all waves

    f32x4 acc[4][4];
#pragma unroll 1
    for (int ct = 0; ct < CT_PER_STRIP; ++ct) {
        const int colTile = strip * CT_PER_STRIP + ct;
        const int col0 = colTile * BN;
        const char* bp = bRow + (size_t)col0 * (DIM * 2);
#pragma unroll
        for (int mi = 0; mi < 4; ++mi)
#pragma unroll
            for (int ni = 0; ni < 4; ++ni) acc[mi][ni] = f32x4{0.f, 0.f, 0.f, 0.f};

#pragma unroll
        for (int kt = 0; kt < 8; ++kt) {
            bf16x8 af[4], bfr[4];
#pragma unroll
            for (int ni = 0; ni < 4; ++ni)
                bfr[ni] = *(const bf16x8*)(bp + ni * (16 * DIM * 2) + kt * 64);
#pragma unroll
            for (int mi = 0; mi < 4; ++mi)
                af[mi] = *(const bf16x8*)((const char*)As + kt * 8192 + aBase + mi * 1024);
            __builtin_amdgcn_s_setprio(1);
#pragma unroll
            for (int mi = 0; mi < 4; ++mi)
#pragma unroll
                for (int ni = 0; ni < 4; ++ni)
                    acc[mi][ni] = __builtin_amdgcn_mfma_f32_16x16x32_bf16(
                        af[mi], bfr[ni], acc[mi][ni], 0, 0, 0);
            __builtin_amdgcn_s_setprio(0);
        }

        // epilogue: exp + running row sums (C/D layout: row = quad*4+reg, col = lc).
        // Barrier-free: this VALU phase overlaps other waves' MFMA phases.
        const bool special = (colTile == rt) || (colTile == posTile);
#pragma unroll
        for (int mi = 0; mi < 4; ++mi) {
#pragma unroll
            for (int ni = 0; ni < 4; ++ni) {
                f32x4 a = acc[mi][ni];
#pragma unroll
                for (int r = 0; r < 4; ++r) {
                    float logit = a[r] * INV_T;
                    float e = __expf(logit);
                    if (special) {
                        int gr = row0 + wr * 64 + mi * 16 + quad * 4 + r;
                        int gc = col0 + wc * 64 + ni * 16 + lc;
                        if (gc == ((gr + B_ROWS) & (TWOB - 1))) pos[gr] = logit;
                        if (gr == gc) e = 0.0f;    // diagonal mask
                    }
                    rsum[mi][r] += e;
                }
            }
        }
    }

    // all ds_reads of As are done; alias rowsumL onto As
    __syncthreads();
    float* rowsumL = (float*)As;         // [2][BM]
#pragma unroll
    for (int mi = 0; mi < 4; ++mi) {
#pragma unroll
        for (int r = 0; r < 4; ++r) {
            float v = rsum[mi][r];
            v += __shfl_xor(v, 1);
            v += __shfl_xor(v, 2);
            v += __shfl_xor(v, 4);
            v += __shfl_xor(v, 8);
            if (lc == 0) rowsumL[wc * BM + wr * 64 + mi * 16 + quad * 4 + r] = v;
        }
    }
    __syncthreads();
    if (tid < BM)
        strip_sums[(size_t)strip * TWOB + row0 + tid] = rowsumL[tid] + rowsumL[BM + tid];
}

// ---------------- kernel 3: loss = mean(log(sumexp) - pos) ----------------
// 32 blocks x 256 threads, one row per thread. Device-scope atomic accumulation;
// last block to finish writes the mean. Accumulators zeroed by normalize_k.
__global__ __launch_bounds__(256) void finalize_k(const float* __restrict__ strip_sums,
                                                  const float* __restrict__ pos,
                                                  float* __restrict__ loss_acc,
                                                  unsigned int* __restrict__ counter,
                                                  float* __restrict__ out) {
    __shared__ float wsums[4];
    const int tid = threadIdx.x;
    const int r   = blockIdx.x * 256 + tid;
    float s = 0.0f;
#pragma unroll
    for (int st = 0; st < NSTRIP; ++st) s += strip_sums[(size_t)st * TWOB + r];
    float local = logf(s) - pos[r];
#pragma unroll
    for (int off = 32; off >= 1; off >>= 1) local += __shfl_xor(local, off);
    if ((tid & 63) == 0) wsums[tid >> 6] = local;
    __syncthreads();
    if (tid == 0) {
        float bsum = wsums[0] + wsums[1] + wsums[2] + wsums[3];
        atomicAdd(loss_acc, bsum);
        __threadfence();                              // order loss add before counter add
        unsigned int done = atomicAdd(counter, 1u);
        if (done == gridDim.x - 1) {
            float total = atomicAdd(loss_acc, 0.0f);  // device-scope atomic read
            out[0] = total / (float)TWOB;
        }
    }
}

extern "C" void kernel_launch(void* const* d_in, const int* in_sizes, int n_in,
                              void* d_out, int out_size, void* d_ws, size_t ws_size,
                              hipStream_t stream) {
    const float* zi = (const float*)d_in[0];
    const float* zj = (const float*)d_in[1];
    // ws layout: zn (4 MB) | pos (32 KB) | strip_sums (256 KB) | loss_acc | counter
    unsigned short* zn = (unsigned short*)d_ws;
    float* pos        = (float*)((char*)d_ws + (size_t)TWOB * DIM * 2);
    float* strip_sums = pos + TWOB;
    float* loss_acc   = strip_sums + (size_t)NSTRIP * TWOB;
    unsigned int* counter = (unsigned int*)(loss_acc + 1);
    float* out = (float*)d_out;

    normalize_k<<<dim3(TWOB / 4), 256, 0, stream>>>(zi, zj, zn, loss_acc, counter);
    ntxent_main<<<dim3(64, NSTRIP), 256, 0, stream>>>(zn, pos, strip_sums);
    finalize_k<<<dim3(TWOB / 256), 256, 0, stream>>>(strip_sums, pos, loss_acc, counter, out);
}

// Round 3
// 120.622 us; speedup vs baseline: 1.0984x; 1.0984x over previous
//
#include <hip/hip_runtime.h>
#include <hip/hip_bf16.h>

#define B_ROWS 4096
#define TWOB   8192
#define DIM    256
#define INV_T  14.285714285714286f  // 1/0.07

#define BM 128
#define BN 128
#define NSTRIP 8
#define CT_PER_STRIP 8    // (8192/128)/NSTRIP
#define NCHUNK 64         // total k-steps per block = CT_PER_STRIP * 8

typedef __bf16 bf16x8 __attribute__((ext_vector_type(8)));
typedef float  f32x4  __attribute__((ext_vector_type(4)));

// ---------------- kernel 1: row L2-normalize, fp32 -> bf16 ----------------
// Also zeroes the finalize accumulators (ws is re-poisoned 0xAA before every launch).
__global__ __launch_bounds__(256) void normalize_k(const float* __restrict__ zi,
                                                   const float* __restrict__ zj,
                                                   unsigned short* __restrict__ zn,
                                                   float* __restrict__ loss_acc,
                                                   unsigned int* __restrict__ counter) {
    if (blockIdx.x == 0 && threadIdx.x == 0) {
        loss_acc[0] = 0.0f;
        counter[0]  = 0u;
    }
    int wave = threadIdx.x >> 6;
    int lane = threadIdx.x & 63;
    int row  = blockIdx.x * 4 + wave;             // 2048 blocks * 4 waves = 8192 rows
    const float* src = (row < B_ROWS) ? (zi + (size_t)row * DIM)
                                      : (zj + (size_t)(row - B_ROWS) * DIM);
    float4 v = reinterpret_cast<const float4*>(src)[lane];   // 64 lanes * 4 = 256
    float ss = v.x * v.x + v.y * v.y + v.z * v.z + v.w * v.w;
#pragma unroll
    for (int off = 32; off >= 1; off >>= 1) ss += __shfl_xor(ss, off);
    float norm = sqrtf(ss);
    norm = fmaxf(norm, 1e-8f);                    // COS_EPS
    float inv = 1.0f / norm;
    ushort4 o;
    o.x = __builtin_bit_cast(unsigned short, __float2bfloat16(v.x * inv));
    o.y = __builtin_bit_cast(unsigned short, __float2bfloat16(v.y * inv));
    o.z = __builtin_bit_cast(unsigned short, __float2bfloat16(v.z * inv));
    o.w = __builtin_bit_cast(unsigned short, __float2bfloat16(v.w * inv));
    reinterpret_cast<ushort4*>(zn)[(size_t)row * 64 + lane] = o;
}

// ---------------- kernel 2: flash NT-Xent main (A-in-registers, 4-deep B ring) ----------------
// R0 post-mortem: the per-kt __syncthreads forced vmcnt(0) drains of a B stage issued
// only ~310 cyc earlier (L2 latency 200-500) -> MfmaUtil 26%. R2 post-mortem: direct
// per-lane B loads from L2 are latency-exposed (17%). Fix: A fragments live in
// REGISTERS (128 VGPR, loaded once from L2, static indices), freeing A's 64 KB of LDS;
// B gets a 4-deep ring (32 KB) staged 3 chunks ahead with raw s_barrier + counted
// s_waitcnt vmcnt(4) -- loads stay in flight across barriers, never drained to 0
// (guide T3+T4). pos[] stores deferred to regs so stage loads are the ONLY in-loop
// VMEM ops (exact vmcnt accounting). LDS per-kt traffic halves (4 ds_reads, 0 for A).
__global__ __launch_bounds__(256, 2) void ntxent_main(const unsigned short* __restrict__ znu,
                                                      float* __restrict__ pos,
                                                      float* __restrict__ strip_sums) {
    const __bf16* zn = (const __bf16*)znu;
    __shared__ __attribute__((aligned(16))) __bf16 Bs[4][BN * 32];   // 4-deep ring, 32 KB

    const int tid  = threadIdx.x;
    const int wave = tid >> 6;
    const int lane = tid & 63;
    const int wr = wave >> 1, wc = wave & 1;
    const int quad = lane >> 4, lc = lane & 15;
    const int rt    = blockIdx.x;        // row-tile 0..63
    const int strip = blockIdx.y;        // 0..NSTRIP-1
    const int row0  = rt * BM;
    const int posTile = (rt + 32) & 63;  // col-tile holding (row+4096) mod 8192

    // ---- A fragments -> registers (issued FIRST so the later vmcnt(4) covers them) ----
    // MFMA A-operand layout: lane l holds row (l&15), k-bytes (l>>4)*16 of each 16x32 tile.
    // Per (mi,kt): global row row0 + wr*64 + mi*16 + lc, byte offset kt*64 + quad*16.
    bf16x8 areg[4][8];
    {
        const char* abase = (const char*)zn + (size_t)(row0 + wr * 64 + lc) * (DIM * 2) + quad * 16;
#pragma unroll
        for (int mi = 0; mi < 4; ++mi)
#pragma unroll
            for (int kt = 0; kt < 8; ++kt)
                areg[mi][kt] = *(const bf16x8*)(abase + (size_t)mi * 16 * (DIM * 2) + kt * 64);
    }

    // staging: per-lane global element offsets (involution swizzle, proven in R0/R2).
    int stg_off[2];
#pragma unroll
    for (int t = 0; t < 2; ++t) {
        int c  = (wave * 2 + t) * 64 + lane;
        int m  = c >> 2;
        int kc = (c & 3) ^ ((m & 3) ^ ((m >> 2) & 3));
        stg_off[t] = m * DIM + kc * 8;
    }

    // fragment-read byte offsets within one 8KB B chunk (same swizzle geometry as A,
    // which R2 measured conflict-free: 262K total)
    const int sw    = (lc & 3) ^ ((lc >> 2) & 3);
    const int bBase = (wc * 64 + lc) * 64 + ((quad ^ sw) * 16);

// stage global chunk C (k-step index 0..63): colTile = strip*8 + (C>>3), kt = C&7, buf = C&3
#define STAGE(C) do { \
        const int col0_ = (strip * CT_PER_STRIP + ((C) >> 3)) * BN; \
        _Pragma("unroll") \
        for (int t_ = 0; t_ < 2; ++t_) { \
            const int j_ = wave * 2 + t_; \
            const __bf16* gb_ = zn + col0_ * DIM + ((C) & 7) * 32 + stg_off[t_]; \
            __builtin_amdgcn_global_load_lds( \
                (const __attribute__((address_space(1))) void*)gb_, \
                (__attribute__((address_space(3))) void*)((char*)Bs + ((C) & 3) * 8192 + j_ * 1024), 16, 0, 0); \
        } } while (0)

// one k-step: counted wait (my chunk T landed; 2-3 stages stay in flight) -> raw
// barrier (all waves' chunk T complete AND all done reading T-1 -> ring slot (T+3)&3
// is reusable) -> sched fence -> issue stage T+3 -> 4 ds_reads -> 16 MFMA.
#define KSTEP(T, KT, WAITASM, DOSTAGE) do { \
        WAITASM; \
        __builtin_amdgcn_s_barrier(); \
        __builtin_amdgcn_sched_barrier(0); \
        if (DOSTAGE) STAGE((T) + 3); \
        bf16x8 bfr_[4]; \
        _Pragma("unroll") \
        for (int ni = 0; ni < 4; ++ni) \
            bfr_[ni] = *(const bf16x8*)((const char*)Bs + ((T) & 3) * 8192 + bBase + ni * 1024); \
        __builtin_amdgcn_s_setprio(1); \
        _Pragma("unroll") \
        for (int mi = 0; mi < 4; ++mi) \
            _Pragma("unroll") \
            for (int ni = 0; ni < 4; ++ni) \
                acc[mi][ni] = __builtin_amdgcn_mfma_f32_16x16x32_bf16( \
                    areg[mi][KT], bfr_[ni], acc[mi][ni], 0, 0, 0); \
        __builtin_amdgcn_s_setprio(0); \
    } while (0)

#define VM4 asm volatile("s_waitcnt vmcnt(4)" ::: "memory")
#define VM2 asm volatile("s_waitcnt vmcnt(2)" ::: "memory")
#define VM0 asm volatile("s_waitcnt vmcnt(0)" ::: "memory")

// per-ct epilogue: exp + running row sums; pos logit captured to registers (no store).
#define EPILOGUE(COLTILE, COL0) do { \
        const bool special_ = ((COLTILE) == rt) || ((COLTILE) == posTile); \
        _Pragma("unroll") \
        for (int mi = 0; mi < 4; ++mi) { \
            _Pragma("unroll") \
            for (int ni = 0; ni < 4; ++ni) { \
                f32x4 a_ = acc[mi][ni]; \
                _Pragma("unroll") \
                for (int r = 0; r < 4; ++r) { \
                    float logit_ = a_[r] * INV_T; \
                    float e_ = __expf(logit_); \
                    if (special_) { \
                        int gr_ = row0 + wr * 64 + mi * 16 + quad * 4 + r; \
                        int gc_ = (COL0) + wc * 64 + ni * 16 + lc; \
                        if (gc_ == ((gr_ + B_ROWS) & (TWOB - 1))) { posv[mi] = logit_; posm[mi] = gr_; } \
                        if (gr_ == gc_) e_ = 0.0f; \
                    } \
                    rsum[mi][r] += e_; \
                } \
            } \
        } } while (0)

    // prologue: 3-deep prefetch (A loads are older -> vmcnt(4) at step 0 drains them too)
    STAGE(0); STAGE(1); STAGE(2);

    float rsum[4][4];
    float posv[4] = {0.f, 0.f, 0.f, 0.f};
    int   posm[4] = {-1, -1, -1, -1};
#pragma unroll
    for (int mi = 0; mi < 4; ++mi)
#pragma unroll
        for (int r = 0; r < 4; ++r) rsum[mi][r] = 0.0f;

    f32x4 acc[4][4];
#pragma unroll 1
    for (int ct = 0; ct < CT_PER_STRIP - 1; ++ct) {
        const int colTile = strip * CT_PER_STRIP + ct;
        const int col0 = colTile * BN;
#pragma unroll
        for (int mi = 0; mi < 4; ++mi)
#pragma unroll
            for (int ni = 0; ni < 4; ++ni) acc[mi][ni] = f32x4{0.f, 0.f, 0.f, 0.f};

        KSTEP(ct * 8 + 0, 0, VM4, 1);
        KSTEP(ct * 8 + 1, 1, VM4, 1);
        KSTEP(ct * 8 + 2, 2, VM4, 1);
        KSTEP(ct * 8 + 3, 3, VM4, 1);
        KSTEP(ct * 8 + 4, 4, VM4, 1);
        KSTEP(ct * 8 + 5, 5, VM4, 1);
        KSTEP(ct * 8 + 6, 6, VM4, 1);
        KSTEP(ct * 8 + 7, 7, VM4, 1);

        EPILOGUE(colTile, col0);
    }
    {   // peeled last ct: stage guard off past chunk 63; tail drains 4 -> 2 -> 0
        const int colTile = strip * CT_PER_STRIP + 7;
        const int col0 = colTile * BN;
#pragma unroll
        for (int mi = 0; mi < 4; ++mi)
#pragma unroll
            for (int ni = 0; ni < 4; ++ni) acc[mi][ni] = f32x4{0.f, 0.f, 0.f, 0.f};

        KSTEP(56, 0, VM4, 1);
        KSTEP(57, 1, VM4, 1);
        KSTEP(58, 2, VM4, 1);
        KSTEP(59, 3, VM4, 1);
        KSTEP(60, 4, VM4, 1);
        KSTEP(61, 5, VM4, 0);
        KSTEP(62, 6, VM2, 0);
        KSTEP(63, 7, VM0, 0);

        EPILOGUE(colTile, col0);
    }

    // deferred pos stores (each (row, row+B) cell is owned by exactly one thread)
#pragma unroll
    for (int mi = 0; mi < 4; ++mi)
        if (posm[mi] >= 0) pos[posm[mi]] = posv[mi];

    // all ds_reads of Bs are done; alias rowsumL onto Bs
    __syncthreads();
    float* rowsumL = (float*)Bs;         // [2][BM]
#pragma unroll
    for (int mi = 0; mi < 4; ++mi) {
#pragma unroll
        for (int r = 0; r < 4; ++r) {
            float v = rsum[mi][r];
            v += __shfl_xor(v, 1);
            v += __shfl_xor(v, 2);
            v += __shfl_xor(v, 4);
            v += __shfl_xor(v, 8);
            if (lc == 0) rowsumL[wc * BM + wr * 64 + mi * 16 + quad * 4 + r] = v;
        }
    }
    __syncthreads();
    if (tid < BM)
        strip_sums[(size_t)strip * TWOB + row0 + tid] = rowsumL[tid] + rowsumL[BM + tid];
}

// ---------------- kernel 3: loss = mean(log(sumexp) - pos) ----------------
// 32 blocks x 256 threads, one row per thread. Device-scope atomic accumulation;
// last block to finish writes the mean. Accumulators zeroed by normalize_k.
__global__ __launch_bounds__(256) void finalize_k(const float* __restrict__ strip_sums,
                                                  const float* __restrict__ pos,
                                                  float* __restrict__ loss_acc,
                                                  unsigned int* __restrict__ counter,
                                                  float* __restrict__ out) {
    __shared__ float wsums[4];
    const int tid = threadIdx.x;
    const int r   = blockIdx.x * 256 + tid;
    float s = 0.0f;
#pragma unroll
    for (int st = 0; st < NSTRIP; ++st) s += strip_sums[(size_t)st * TWOB + r];
    float local = logf(s) - pos[r];
#pragma unroll
    for (int off = 32; off >= 1; off >>= 1) local += __shfl_xor(local, off);
    if ((tid & 63) == 0) wsums[tid >> 6] = local;
    __syncthreads();
    if (tid == 0) {
        float bsum = wsums[0] + wsums[1] + wsums[2] + wsums[3];
        atomicAdd(loss_acc, bsum);
        __threadfence();                              // order loss add before counter add
        unsigned int done = atomicAdd(counter, 1u);
        if (done == gridDim.x - 1) {
            float total = atomicAdd(loss_acc, 0.0f);  // device-scope atomic read
            out[0] = total / (float)TWOB;
        }
    }
}

extern "C" void kernel_launch(void* const* d_in, const int* in_sizes, int n_in,
                              void* d_out, int out_size, void* d_ws, size_t ws_size,
                              hipStream_t stream) {
    const float* zi = (const float*)d_in[0];
    const float* zj = (const float*)d_in[1];
    // ws layout: zn (4 MB) | pos (32 KB) | strip_sums (256 KB) | loss_acc | counter
    unsigned short* zn = (unsigned short*)d_ws;
    float* pos        = (float*)((char*)d_ws + (size_t)TWOB * DIM * 2);
    float* strip_sums = pos + TWOB;
    float* loss_acc   = strip_sums + (size_t)NSTRIP * TWOB;
    unsigned int* counter = (unsigned int*)(loss_acc + 1);
    float* out = (float*)d_out;

    normalize_k<<<dim3(TWOB / 4), 256, 0, stream>>>(zi, zj, zn, loss_acc, counter);
    ntxent_main<<<dim3(64, NSTRIP), 256, 0, stream>>>(zn, pos, strip_sums);
    finalize_k<<<dim3(TWOB / 256), 256, 0, stream>>>(strip_sums, pos, loss_acc, counter, out);
}

// Round 4
// 109.794 us; speedup vs baseline: 1.2068x; 1.0986x over previous
//
#include <hip/hip_runtime.h>
#include <hip/hip_bf16.h>

#define B_ROWS 4096
#define TWOB   8192
#define DIM    256
#define INV_T  14.285714285714286f  // 1/0.07

#define BM 128            // block row tile
#define BN 256            // block col tile
#define NSTRIP 4          // col strips: 8192/4 = 2048 cols = 8 ct of 256
#define CT_PER_STRIP 8

typedef __bf16 bf16x8 __attribute__((ext_vector_type(8)));
typedef float  f32x4  __attribute__((ext_vector_type(4)));

// ---------------- kernel 1: row L2-normalize, fp32 -> bf16 ----------------
__global__ __launch_bounds__(256) void normalize_k(const float* __restrict__ zi,
                                                   const float* __restrict__ zj,
                                                   unsigned short* __restrict__ zn,
                                                   float* __restrict__ loss_acc,
                                                   unsigned int* __restrict__ counter) {
    if (blockIdx.x == 0 && threadIdx.x == 0) {
        loss_acc[0] = 0.0f;
        counter[0]  = 0u;
    }
    int wave = threadIdx.x >> 6;
    int lane = threadIdx.x & 63;
    int row  = blockIdx.x * 4 + wave;
    const float* src = (row < B_ROWS) ? (zi + (size_t)row * DIM)
                                      : (zj + (size_t)(row - B_ROWS) * DIM);
    float4 v = reinterpret_cast<const float4*>(src)[lane];
    float ss = v.x * v.x + v.y * v.y + v.z * v.z + v.w * v.w;
#pragma unroll
    for (int off = 32; off >= 1; off >>= 1) ss += __shfl_xor(ss, off);
    float norm = sqrtf(ss);
    norm = fmaxf(norm, 1e-8f);                    // COS_EPS
    float inv = 1.0f / norm;
    ushort4 o;
    o.x = __builtin_bit_cast(unsigned short, __float2bfloat16(v.x * inv));
    o.y = __builtin_bit_cast(unsigned short, __float2bfloat16(v.y * inv));
    o.z = __builtin_bit_cast(unsigned short, __float2bfloat16(v.z * inv));
    o.w = __builtin_bit_cast(unsigned short, __float2bfloat16(v.w * inv));
    reinterpret_cast<ushort4*>(zn)[(size_t)row * 64 + lane] = o;
}

// ---------------- kernel 2: flash NT-Xent main ----------------
// 512 thr / 8 waves (2M x 4N), block tile 128x256, grid 64x4 = 256 blocks = 1/CU.
// A (128x256 = 64 KB) LDS-resident, staged once. B: 4-deep ring of 16 KB chunks
// (256 cols x 32 k), staged 3 chunks ahead; raw s_barrier + counted s_waitcnt
// vmcnt(4) (never 0 mid-loop) -> stages stay in flight across barriers (T3+T4).
// R3 verified this sync skeleton (absmax 0.0); R3's failure was A-in-reg spills
// (WRITE_SIZE 25 MB) -> A back in LDS, regs ~130, no spill.
__global__ __launch_bounds__(512, 2) void ntxent_main(const unsigned short* __restrict__ znu,
                                                      float* __restrict__ pos,
                                                      float* __restrict__ strip_sums) {
    const __bf16* zn = (const __bf16*)znu;
    __shared__ __attribute__((aligned(16))) __bf16 As[8][BM * 32];   // 8 x 8 KB = 64 KB
    __shared__ __attribute__((aligned(16))) __bf16 Bs[4][BN * 32];   // 4 x 16 KB ring = 64 KB

    const int tid  = threadIdx.x;
    const int wave = tid >> 6;               // 0..7
    const int lane = tid & 63;
    const int wr = wave >> 2, wc = wave & 3; // 2 x 4 wave grid, wave tile 64x64
    const int quad = lane >> 4, lc = lane & 15;
    const int rt    = blockIdx.x;            // row tile 0..63 (128 rows)
    const int strip = blockIdx.y;            // 0..3 (2048 cols each)
    const int row0  = rt * BM;
    const int diagT = rt >> 1;               // 256-col tile containing the diagonal
    const int posT  = ((rt >> 1) + 16) & 31; // 256-col tile containing (row+4096)&8191

    // A staging: one 16B load per thread per 8 KB chunk; c = tid
    // involution swizzle: m = c>>2, kc_g = (c&3) ^ sw(m), sw(m) = (m&3)^((m>>2)&3)
    int stgA;
    {
        int m  = tid >> 2;
        int kc = (tid & 3) ^ ((m & 3) ^ ((m >> 2) & 3));
        stgA = m * DIM + kc * 8;
    }
    // B staging: two 16B loads per thread per 16 KB chunk; c = (wave*2+t)*64+lane
    int stgB[2];
#pragma unroll
    for (int t = 0; t < 2; ++t) {
        int c  = (wave * 2 + t) * 64 + lane;   // 0..1023
        int m  = c >> 2;                       // row 0..255
        int kc = (c & 3) ^ ((m & 3) ^ ((m >> 2) & 3));
        stgB[t] = m * DIM + kc * 8;
    }

    // ---- prologue: stage all of A (8 chunks, issued first so VM4 at step 0 drains it) ----
#pragma unroll
    for (int kt = 0; kt < 8; ++kt) {
        const __bf16* ga = zn + row0 * DIM + kt * 32 + stgA;
        __builtin_amdgcn_global_load_lds(
            (const __attribute__((address_space(1))) void*)ga,
            (__attribute__((address_space(3))) void*)((char*)As + kt * 8192 + wave * 1024), 16, 0, 0);
    }

// stage B chunk C (0..63): colTile256 = strip*8 + (C>>3), kt = C&7, ring slot = C&3
#define STAGE(C) do { \
        const int col0_ = (strip * 8 + ((C) >> 3)) * BN; \
        _Pragma("unroll") \
        for (int t_ = 0; t_ < 2; ++t_) { \
            const int j_ = wave * 2 + t_; \
            const __bf16* gb_ = zn + col0_ * DIM + ((C) & 7) * 32 + stgB[t_]; \
            __builtin_amdgcn_global_load_lds( \
                (const __attribute__((address_space(1))) void*)gb_, \
                (__attribute__((address_space(3))) void*)((char*)Bs + ((C) & 3) * 16384 + j_ * 1024), 16, 0, 0); \
        } } while (0)

    // fragment-read byte offsets (same proven swizzle; conflict-free per R2's 262K)
    const int sw    = (lc & 3) ^ ((lc >> 2) & 3);
    const int aBase = (wr * 64 + lc) * 64 + ((quad ^ sw) * 16);   // + mi*1024 + kt*8192
    const int bBase = (wc * 64 + lc) * 64 + ((quad ^ sw) * 16);   // + ni*1024 + slot*16384

// one k-step: counted wait (chunk T landed; 2 stages stay in flight) -> raw barrier
// (all waves' chunk-T writes done AND all done reading T-1 -> slot (T+3)&3 reusable)
// -> sched fence -> issue stage T+3 -> 8 ds_read_b128 -> 16 MFMA.
#define KSTEP(T, WAITASM, DOSTAGE) do { \
        WAITASM; \
        __builtin_amdgcn_s_barrier(); \
        __builtin_amdgcn_sched_barrier(0); \
        if (DOSTAGE) STAGE((T) + 3); \
        bf16x8 af_[4], bfr_[4]; \
        _Pragma("unroll") \
        for (int ni = 0; ni < 4; ++ni) \
            bfr_[ni] = *(const bf16x8*)((const char*)Bs + ((T) & 3) * 16384 + bBase + ni * 1024); \
        _Pragma("unroll") \
        for (int mi = 0; mi < 4; ++mi) \
            af_[mi] = *(const bf16x8*)((const char*)As + ((T) & 7) * 8192 + aBase + mi * 1024); \
        __builtin_amdgcn_s_setprio(1); \
        _Pragma("unroll") \
        for (int mi = 0; mi < 4; ++mi) \
            _Pragma("unroll") \
            for (int ni = 0; ni < 4; ++ni) \
                acc[mi][ni] = __builtin_amdgcn_mfma_f32_16x16x32_bf16( \
                    af_[mi], bfr_[ni], acc[mi][ni], 0, 0, 0); \
        __builtin_amdgcn_s_setprio(0); \
    } while (0)

#define VM4 asm volatile("s_waitcnt vmcnt(4)" ::: "memory")
#define VM2 asm volatile("s_waitcnt vmcnt(2)" ::: "memory")
#define VM0 asm volatile("s_waitcnt vmcnt(0)" ::: "memory")

// per-ct epilogue: exp + running row sums (C/D: row = quad*4+r, col = lc); pos -> regs
#define EPILOGUE(COLTILE, COL0) do { \
        const bool special_ = ((COLTILE) == diagT) || ((COLTILE) == posT); \
        _Pragma("unroll") \
        for (int mi = 0; mi < 4; ++mi) { \
            _Pragma("unroll") \
            for (int ni = 0; ni < 4; ++ni) { \
                f32x4 a_ = acc[mi][ni]; \
                _Pragma("unroll") \
                for (int r = 0; r < 4; ++r) { \
                    float logit_ = a_[r] * INV_T; \
                    float e_ = __expf(logit_); \
                    if (special_) { \
                        int gr_ = row0 + wr * 64 + mi * 16 + quad * 4 + r; \
                        int gc_ = (COL0) + wc * 64 + ni * 16 + lc; \
                        if (gc_ == ((gr_ + B_ROWS) & (TWOB - 1))) { posv[mi] = logit_; posm[mi] = gr_; } \
                        if (gr_ == gc_) e_ = 0.0f; \
                    } \
                    rsum[mi][r] += e_; \
                } \
            } \
        } } while (0)

    // prologue B: 3-deep prefetch
    STAGE(0); STAGE(1); STAGE(2);

    float rsum[4][4];
    float posv[4] = {0.f, 0.f, 0.f, 0.f};
    int   posm[4] = {-1, -1, -1, -1};
#pragma unroll
    for (int mi = 0; mi < 4; ++mi)
#pragma unroll
        for (int r = 0; r < 4; ++r) rsum[mi][r] = 0.0f;

    f32x4 acc[4][4];
#pragma unroll 1
    for (int ct = 0; ct < CT_PER_STRIP - 1; ++ct) {
        const int colTile = strip * 8 + ct;
        const int col0 = colTile * BN;
#pragma unroll
        for (int mi = 0; mi < 4; ++mi)
#pragma unroll
            for (int ni = 0; ni < 4; ++ni) acc[mi][ni] = f32x4{0.f, 0.f, 0.f, 0.f};

        KSTEP(ct * 8 + 0, VM4, 1);
        KSTEP(ct * 8 + 1, VM4, 1);
        KSTEP(ct * 8 + 2, VM4, 1);
        KSTEP(ct * 8 + 3, VM4, 1);
        KSTEP(ct * 8 + 4, VM4, 1);
        KSTEP(ct * 8 + 5, VM4, 1);
        KSTEP(ct * 8 + 6, VM4, 1);
        KSTEP(ct * 8 + 7, VM4, 1);

        EPILOGUE(colTile, col0);
    }
    {   // peeled last ct: stop staging past chunk 63; tail drains 4 -> 2 -> 0
        const int colTile = strip * 8 + 7;
        const int col0 = colTile * BN;
#pragma unroll
        for (int mi = 0; mi < 4; ++mi)
#pragma unroll
            for (int ni = 0; ni < 4; ++ni) acc[mi][ni] = f32x4{0.f, 0.f, 0.f, 0.f};

        KSTEP(56, VM4, 1);
        KSTEP(57, VM4, 1);
        KSTEP(58, VM4, 1);
        KSTEP(59, VM4, 1);
        KSTEP(60, VM4, 1);
        KSTEP(61, VM4, 0);
        KSTEP(62, VM2, 0);
        KSTEP(63, VM0, 0);

        EPILOGUE(colTile, col0);
    }

    // deferred pos stores (each (row, row+B) cell owned by exactly one thread)
#pragma unroll
    for (int mi = 0; mi < 4; ++mi)
        if (posm[mi] >= 0) pos[posm[mi]] = posv[mi];

    // all LDS reads done; alias rowsumL onto As
    __syncthreads();
    float* rowsumL = (float*)As;         // [4 wc][BM]
#pragma unroll
    for (int mi = 0; mi < 4; ++mi) {
#pragma unroll
        for (int r = 0; r < 4; ++r) {
            float v = rsum[mi][r];
            v += __shfl_xor(v, 1);
            v += __shfl_xor(v, 2);
            v += __shfl_xor(v, 4);
            v += __shfl_xor(v, 8);
            if (lc == 0) rowsumL[wc * BM + wr * 64 + mi * 16 + quad * 4 + r] = v;
        }
    }
    __syncthreads();
    if (tid < BM)
        strip_sums[(size_t)strip * TWOB + row0 + tid] =
            rowsumL[tid] + rowsumL[BM + tid] + rowsumL[2 * BM + tid] + rowsumL[3 * BM + tid];
}

// ---------------- kernel 3: loss = mean(log(sumexp) - pos) ----------------
__global__ __launch_bounds__(256) void finalize_k(const float* __restrict__ strip_sums,
                                                  const float* __restrict__ pos,
                                                  float* __restrict__ loss_acc,
                                                  unsigned int* __restrict__ counter,
                                                  float* __restrict__ out) {
    __shared__ float wsums[4];
    const int tid = threadIdx.x;
    const int r   = blockIdx.x * 256 + tid;
    float s = 0.0f;
#pragma unroll
    for (int st = 0; st < NSTRIP; ++st) s += strip_sums[(size_t)st * TWOB + r];
    float local = logf(s) - pos[r];
#pragma unroll
    for (int off = 32; off >= 1; off >>= 1) local += __shfl_xor(local, off);
    if ((tid & 63) == 0) wsums[tid >> 6] = local;
    __syncthreads();
    if (tid == 0) {
        float bsum = wsums[0] + wsums[1] + wsums[2] + wsums[3];
        atomicAdd(loss_acc, bsum);
        __threadfence();                              // order loss add before counter add
        unsigned int done = atomicAdd(counter, 1u);
        if (done == gridDim.x - 1) {
            float total = atomicAdd(loss_acc, 0.0f);  // device-scope atomic read
            out[0] = total / (float)TWOB;
        }
    }
}

extern "C" void kernel_launch(void* const* d_in, const int* in_sizes, int n_in,
                              void* d_out, int out_size, void* d_ws, size_t ws_size,
                              hipStream_t stream) {
    const float* zi = (const float*)d_in[0];
    const float* zj = (const float*)d_in[1];
    // ws layout: zn (4 MB) | pos (32 KB) | strip_sums (128 KB) | loss_acc | counter
    unsigned short* zn = (unsigned short*)d_ws;
    float* pos        = (float*)((char*)d_ws + (size_t)TWOB * DIM * 2);
    float* strip_sums = pos + TWOB;
    float* loss_acc   = strip_sums + (size_t)NSTRIP * TWOB;
    unsigned int* counter = (unsigned int*)(loss_acc + 1);
    float* out = (float*)d_out;

    normalize_k<<<dim3(TWOB / 4), 256, 0, stream>>>(zi, zj, zn, loss_acc, counter);
    ntxent_main<<<dim3(64, NSTRIP), 512, 0, stream>>>(zn, pos, strip_sums);
    finalize_k<<<dim3(TWOB / 256), 256, 0, stream>>>(strip_sums, pos, loss_acc, counter, out);
}